// Round 2
// baseline (627.646 us; speedup 1.0000x reference)
//
#include <hip/hip_runtime.h>

// EMA recurrence lta[t] = lta[t-1] + w*(x[t]-lta[t-1]) over [B=256, T=60000, C=3] fp32.
// R1 post-mortem: latency-bound (12% HBM BW, 11% occupancy, FETCH == input size).
// R2: CHUNK=64 (938 chunks/row, 240k threads, ~3.7 blocks/CU), each thread owns all
// 3 channels of one (b, chunk) -> dense float4 IO (4 timesteps = 3 x float4), and
// chunk-fastest mapping so warm-up reads hit lines fetched by same-block neighbors
// (L1/L2 absorb the 9x logical read amplification; HBM traffic stays ~368 MB).
// WARM=512 kept: measured absmax 1.95e-3 vs 8.98e-3 threshold at W=512.

#define T_LEN 60000
#define BATCH 256
#define CH    3
#define CHUNK 64
#define WARM  512

__global__ __launch_bounds__(256) void lta_kernel(const float* __restrict__ x,
                                                  float* __restrict__ out,
                                                  int nC, int total) {
    int tid = blockIdx.x * blockDim.x + threadIdx.x;
    if (tid >= total) return;

    int chunk = tid % nC;            // chunk-fastest: block = 256 consecutive chunks
    int b     = tid / nC;

    int t0 = chunk * CHUNK;
    int t1 = t0 + CHUNK;
    if (t1 > T_LEN) t1 = T_LEN;
    int tw = t0 - WARM;
    if (tw < 0) tw = 0;

    const float w = 0.015f;
    const float* __restrict__ base = x + (size_t)b * (T_LEN * CH);

    float y0 = 0.0f, y1 = 0.0f, y2 = 0.0f;

    // ---- Warm-up: (t0 - tw) steps, always a multiple of 4; 3 float4 per 4 steps.
    {
        const float4* __restrict__ p = (const float4*)(base + (size_t)tw * CH);
        int ng = (t0 - tw) >> 2;
        #pragma unroll 4
        for (int g = 0; g < ng; ++g) {
            float4 A = p[3 * g + 0];
            float4 Bq = p[3 * g + 1];
            float4 Cq = p[3 * g + 2];
            y0 = fmaf(w, A.x - y0, y0); y1 = fmaf(w, A.y - y1, y1); y2 = fmaf(w, A.z - y2, y2);
            y0 = fmaf(w, A.w - y0, y0); y1 = fmaf(w, Bq.x - y1, y1); y2 = fmaf(w, Bq.y - y2, y2);
            y0 = fmaf(w, Bq.z - y0, y0); y1 = fmaf(w, Bq.w - y1, y1); y2 = fmaf(w, Cq.x - y2, y2);
            y0 = fmaf(w, Cq.y - y0, y0); y1 = fmaf(w, Cq.z - y1, y1); y2 = fmaf(w, Cq.w - y2, y2);
        }
    }

    // ---- Main chunk: compute + store, (t1 - t0) multiple of 4.
    {
        const float4* __restrict__ p = (const float4*)(base + (size_t)t0 * CH);
        float4* __restrict__ q = (float4*)(out + (size_t)b * (T_LEN * CH) + (size_t)t0 * CH);
        int ng = (t1 - t0) >> 2;
        #pragma unroll 4
        for (int g = 0; g < ng; ++g) {
            float4 A = p[3 * g + 0];
            float4 Bq = p[3 * g + 1];
            float4 Cq = p[3 * g + 2];
            float4 D, E, F;
            y0 = fmaf(w, A.x - y0, y0);  D.x = y0;
            y1 = fmaf(w, A.y - y1, y1);  D.y = y1;
            y2 = fmaf(w, A.z - y2, y2);  D.z = y2;
            y0 = fmaf(w, A.w - y0, y0);  D.w = y0;
            y1 = fmaf(w, Bq.x - y1, y1); E.x = y1;
            y2 = fmaf(w, Bq.y - y2, y2); E.y = y2;
            y0 = fmaf(w, Bq.z - y0, y0); E.z = y0;
            y1 = fmaf(w, Bq.w - y1, y1); E.w = y1;
            y2 = fmaf(w, Cq.x - y2, y2); F.x = y2;
            y0 = fmaf(w, Cq.y - y0, y0); F.y = y0;
            y1 = fmaf(w, Cq.z - y1, y1); F.z = y1;
            y2 = fmaf(w, Cq.w - y2, y2); F.w = y2;
            q[3 * g + 0] = D;
            q[3 * g + 1] = E;
            q[3 * g + 2] = F;
        }
    }
}

extern "C" void kernel_launch(void* const* d_in, const int* in_sizes, int n_in,
                              void* d_out, int out_size, void* d_ws, size_t ws_size,
                              hipStream_t stream) {
    const float* x = (const float*)d_in[0];
    float* out = (float*)d_out;

    const int nC = (T_LEN + CHUNK - 1) / CHUNK;      // 938 (last chunk = 32 steps)
    const int total = BATCH * nC;                    // 240128
    const int block = 256;
    const int grid = (total + block - 1) / block;    // 938

    lta_kernel<<<grid, block, 0, stream>>>(x, out, nC, total);
}

// Round 3
// 321.263 us; speedup vs baseline: 1.9537x; 1.9537x over previous
//
#include <hip/hip_runtime.h>

// EMA lta[t] = lta[t-1] + w*(x[t]-lta[t-1]), [B=256, T=60000, C=3] fp32.
//
// R2 post-mortem: warm-up re-reads with 768B-strided lanes -> FETCH 875 MB (4.8x
// input), L2 thrash. R3: LDS-staged block-level linear scan.
//   y[t] = a*y[t-1] + w*x[t] (a = 1-w)  is linear, so a chunk of L steps is an
//   affine map y_out = A*y_in + V with A = a^L. Each block stages a 3072-step
//   tile into LDS (coalesced float4, each HBM byte read once), 256 threads each
//   reduce 12 steps from zero (pass1), an exact (A,V) scan across threads gives
//   every thread its true carry, pass2 recomputes the 12 steps from that carry
//   and writes back to LDS, then a coalesced float4 store.
// Only block starts use a 512-step warm-up (carry decays as 0.985^512; measured
// absmax 1.95e-3 vs 8.98e-3 threshold). 8 blocks/row = 2048 blocks; 36 KB LDS
// -> 4 blocks/CU, 16 waves/CU.

#define T_LEN    60000
#define BATCH    256
#define CH       3
#define NBLK_ROW 8
#define SEG      7500        // T_LEN / NBLK_ROW, multiple of 4
#define WARM     512
#define LPT      12          // steps per thread per tile (multiple of 4)
#define TS       (256 * LPT) // 3072 steps per tile
#define NTILES   3           // ceil((SEG + WARM) / TS)
#define TILE_F   (TS * CH)   // 9216 floats = 36 KB
#define F4PT     (LPT * CH / 4)  // 9 float4 per thread chunk

__global__ __launch_bounds__(256) void lta_kernel(const float* __restrict__ x,
                                                  float* __restrict__ out) {
    __shared__ float tile[TILE_F];
    __shared__ float waveA[4], waveV0[4], waveV1[4], waveV2[4];
    __shared__ float carry[CH];

    const int tid  = threadIdx.x;
    const int lane = tid & 63;
    const int wv   = tid >> 6;

    const int blk = blockIdx.x;
    const int b   = blk / NBLK_ROW;
    const int q   = blk % NBLK_ROW;

    const int r0 = q * SEG;                          // output start (mult of 4)
    const int r1 = r0 + SEG;                         // output end
    const int w0 = (r0 >= WARM) ? (r0 - WARM) : 0;   // stage start, carry=0 here

    const float w  = 0.015f;
    const float a  = 1.0f - w;                       // 0.985
    const float a4 = (a * a) * (a * a);

    const float* __restrict__ rowx = x   + (size_t)b * (T_LEN * CH);
    float* __restrict__       rowo = out + (size_t)b * (T_LEN * CH);

    if (tid == 0) { carry[0] = 0.f; carry[1] = 0.f; carry[2] = 0.f; }
    __syncthreads();

    for (int tix = 0; tix < NTILES; ++tix) {
        const int s0 = w0 + tix * TS;                // tile step start (mult of 4)
        if (s0 >= r1) break;                         // block-uniform

        // carry from previous tile (end-of-loop sync makes it visible)
        const float C0 = carry[0], C1 = carry[1], C2 = carry[2];

        // ---- stage: coalesced float4 HBM -> LDS (each byte once) ----
        const int valid_end = (s0 + TS < T_LEN) ? (s0 + TS) : T_LEN;
        const int bound_f4  = ((valid_end - s0) * CH) >> 2;
        {
            const float4* __restrict__ gx = (const float4*)(rowx + (size_t)s0 * CH);
            float4* __restrict__ lt = (float4*)tile;
            #pragma unroll
            for (int j = 0; j < TILE_F / 4 / 256; ++j) {   // 9
                int f4 = j * 256 + tid;
                if (f4 < bound_f4) lt[f4] = gx[f4];
            }
        }
        __syncthreads();

        // ---- pass 1: per-thread EMA from zero over its LPT steps ----
        const int t_lo = s0 + LPT * tid;
        int Li = r1 - t_lo;                          // multiple of 4 by construction
        Li = (Li < 0) ? 0 : (Li > LPT ? LPT : Li);
        const int ng = Li >> 2;                      // 0..3 groups of 4 steps

        const float4* __restrict__ lp = (const float4*)tile + tid * F4PT;
        float y0 = 0.f, y1 = 0.f, y2 = 0.f;
        for (int g = 0; g < ng; ++g) {
            float4 A4 = lp[3 * g + 0];
            float4 B4 = lp[3 * g + 1];
            float4 C4 = lp[3 * g + 2];
            y0 = fmaf(w, A4.x - y0, y0); y1 = fmaf(w, A4.y - y1, y1); y2 = fmaf(w, A4.z - y2, y2);
            y0 = fmaf(w, A4.w - y0, y0); y1 = fmaf(w, B4.x - y1, y1); y2 = fmaf(w, B4.y - y2, y2);
            y0 = fmaf(w, B4.z - y0, y0); y1 = fmaf(w, B4.w - y1, y1); y2 = fmaf(w, C4.x - y2, y2);
            y0 = fmaf(w, C4.y - y0, y0); y1 = fmaf(w, C4.z - y1, y1); y2 = fmaf(w, C4.w - y2, y2);
        }
        float AL = 1.0f;
        for (int g = 0; g < ng; ++g) AL *= a4;       // a^Li

        // ---- exact (A,V) scan: within-wave shuffles, then wave totals ----
        // segment transform: y_out = A*y_in + V; compose R after L:
        //   (A,V) = (A_R*A_L, A_R*V_L + V_R)
        float As = AL, V0 = y0, V1 = y1, V2 = y2;    // inclusive accumulator
        #pragma unroll
        for (int d = 1; d < 64; d <<= 1) {
            float Au = __shfl_up(As, d, 64);
            float u0 = __shfl_up(V0, d, 64);
            float u1 = __shfl_up(V1, d, 64);
            float u2 = __shfl_up(V2, d, 64);
            if (lane >= d) {
                V0 = fmaf(As, u0, V0);
                V1 = fmaf(As, u1, V1);
                V2 = fmaf(As, u2, V2);
                As = As * Au;
            }
        }
        if (lane == 63) { waveA[wv] = As; waveV0[wv] = V0; waveV1[wv] = V1; waveV2[wv] = V2; }
        __syncthreads();

        // exclusive within wave (shift inclusive by 1)
        float Ae = __shfl_up(As, 1, 64);
        float e0 = __shfl_up(V0, 1, 64);
        float e1 = __shfl_up(V1, 1, 64);
        float e2 = __shfl_up(V2, 1, 64);
        if (lane == 0) { Ae = 1.f; e0 = 0.f; e1 = 0.f; e2 = 0.f; }

        // prefix over earlier waves: P = T_{wv-1} ∘ ... ∘ T_0
        float Ap = 1.f, p0 = 0.f, p1 = 0.f, p2 = 0.f;
        for (int k = 0; k < wv; ++k) {
            float Ak = waveA[k];
            p0 = fmaf(Ak, p0, waveV0[k]);
            p1 = fmaf(Ak, p1, waveV1[k]);
            p2 = fmaf(Ak, p2, waveV2[k]);
            Ap *= Ak;
        }

        // thread's true carry-in: Y = E ∘ P applied to C
        float Y0 = fmaf(Ae, fmaf(Ap, C0, p0), e0);
        float Y1 = fmaf(Ae, fmaf(Ap, C1, p1), e1);
        float Y2 = fmaf(Ae, fmaf(Ap, C2, p2), e2);

        // next tile's carry: last thread's inclusive ∘ P applied to C
        if (tid == 255) {
            carry[0] = fmaf(As, fmaf(Ap, C0, p0), V0);
            carry[1] = fmaf(As, fmaf(Ap, C1, p1), V1);
            carry[2] = fmaf(As, fmaf(Ap, C2, p2), V2);
        }

        // ---- pass 2: recompute from exact carry, write back to LDS in place ----
        float4* __restrict__ lpw = (float4*)tile + tid * F4PT;
        y0 = Y0; y1 = Y1; y2 = Y2;
        for (int g = 0; g < ng; ++g) {
            float4 A4 = lpw[3 * g + 0];
            float4 B4 = lpw[3 * g + 1];
            float4 C4 = lpw[3 * g + 2];
            float4 D, E, F;
            y0 = fmaf(w, A4.x - y0, y0);  D.x = y0;
            y1 = fmaf(w, A4.y - y1, y1);  D.y = y1;
            y2 = fmaf(w, A4.z - y2, y2);  D.z = y2;
            y0 = fmaf(w, A4.w - y0, y0);  D.w = y0;
            y1 = fmaf(w, B4.x - y1, y1);  E.x = y1;
            y2 = fmaf(w, B4.y - y2, y2);  E.y = y2;
            y0 = fmaf(w, B4.z - y0, y0);  E.z = y0;
            y1 = fmaf(w, B4.w - y1, y1);  E.w = y1;
            y2 = fmaf(w, C4.x - y2, y2);  F.x = y2;
            y0 = fmaf(w, C4.y - y0, y0);  F.y = y0;
            y1 = fmaf(w, C4.z - y1, y1);  F.z = y1;
            y2 = fmaf(w, C4.w - y2, y2);  F.w = y2;
            lpw[3 * g + 0] = D;
            lpw[3 * g + 1] = E;
            lpw[3 * g + 2] = F;
        }
        __syncthreads();

        // ---- coalesced store of [max(s0,r0), r1) ----
        {
            const int slo = (s0 > r0) ? s0 : r0;
            const int shi = (s0 + TS < r1) ? (s0 + TS) : r1;
            const int lo_f4 = ((slo - s0) * CH) >> 2;
            const int hi_f4 = ((shi - s0) * CH) >> 2;
            float4* __restrict__ go = (float4*)(rowo + (size_t)s0 * CH);
            const float4* __restrict__ lt = (const float4*)tile;
            #pragma unroll
            for (int j = 0; j < TILE_F / 4 / 256; ++j) {
                int f4 = j * 256 + tid;
                if (f4 >= lo_f4 && f4 < hi_f4) go[f4] = lt[f4];
            }
        }
        __syncthreads();   // protect tile + carry before next iteration
    }
}

extern "C" void kernel_launch(void* const* d_in, const int* in_sizes, int n_in,
                              void* d_out, int out_size, void* d_ws, size_t ws_size,
                              hipStream_t stream) {
    const float* x = (const float*)d_in[0];
    float* out = (float*)d_out;

    const int grid = BATCH * NBLK_ROW;   // 2048 blocks
    lta_kernel<<<grid, 256, 0, stream>>>(x, out);
}